// Round 1
// baseline (867.065 us; speedup 1.0000x reference)
//
#include <hip/hip_runtime.h>
#include <hip/hip_bf16.h>

// BiologicalBrain: B=64, D=3072, NA=4, A=2048, N=8192
// Strategy: everything memory-bound. Convert fp32 weights -> bf16 on the fly,
// MFMA 16x16x32 GEMMs with per-wave full-M (64) tiles so W/mask stream exactly
// once from HBM. K-split partial buffers for occupancy; fused epilogue.
//
// ws layout (bytes):
//   gate        @ 0         (16 B)
//   Zg bf16     @ 256       (1 MB)
//   x  bf16     @ 1048832   (384 KB)
//   stim parts  @ 1442048   (4 x 2 MB)
//   znext parts @ 9830656   (8 x 2 MB)
//   Z_flat      @ 26607872  (2 MB)   -> total ~27.4 MB

typedef __bf16 bf16x8 __attribute__((ext_vector_type(8)));
typedef float floatx4 __attribute__((ext_vector_type(4)));

#define ZG_ELEMS   524288   // 64*4*2048 = B*N
#define XB_ELEMS   196608   // 64*3072

__global__ void gate_kernel(const float* __restrict__ Z, float* __restrict__ gate) {
    int i = blockIdx.x;  // area 0..3
    float s = 0.f;
    for (int idx = threadIdx.x; idx < 131072; idx += 256) {
        int b = idx >> 11, a = idx & 2047;
        s += fabsf(Z[((size_t)((b << 2) + i) << 11) + a]);
    }
    #pragma unroll
    for (int off = 32; off > 0; off >>= 1) s += __shfl_down(s, off);
    __shared__ float red[4];
    if ((threadIdx.x & 63) == 0) red[threadIdx.x >> 6] = s;
    __syncthreads();
    if (threadIdx.x == 0) {
        float tot = red[0] + red[1] + red[2] + red[3];
        gate[i] = (tot * (1.f / 131072.f) > 0.02f) ? 1.f : 0.f;
    }
}

// Zg = bf16(Z * gate[i]); x -> bf16; zero Z_flat (scatter safety)
__global__ void prep_kernel(const float* __restrict__ Z, const float* __restrict__ x,
                            const float* __restrict__ gate,
                            __bf16* __restrict__ zg, __bf16* __restrict__ xb,
                            float* __restrict__ zflat) {
    int idx = blockIdx.x * 256 + threadIdx.x;
    if (idx < ZG_ELEMS) {
        int i = (idx >> 11) & 3;
        zg[idx] = (__bf16)(Z[idx] * gate[i]);
        zflat[idx] = 0.f;
    } else {
        int k = idx - ZG_ELEMS;
        xb[k] = (__bf16)x[k];
    }
}

// stim GEMM: C[b,n] = sum_d x[b,d] * rw[n,d].  M=64, N=8192, K=3072.
// One wave: n-tile of 16 (cols), all 64 b (4 m-tiles), K-split 4 (768 each, 24 steps).
__global__ __launch_bounds__(256) void stim_kernel(const __bf16* __restrict__ xb,
                                                   const float* __restrict__ rw,
                                                   float* __restrict__ sp) {
    int wave = (blockIdx.x << 2) | (threadIdx.x >> 6);
    int lane = threadIdx.x & 63;
    int col = lane & 15, quad = lane >> 4;
    int ks = wave & 3;
    int ntile = wave >> 2;            // 0..511
    int n = (ntile << 4) | col;
    const float* bp = rw + (size_t)n * 3072 + ks * 768 + quad * 8;
    const bf16x8* ap[4];
    #pragma unroll
    for (int t = 0; t < 4; t++)
        ap[t] = (const bf16x8*)(xb + (size_t)(col + 16 * t) * 3072 + ks * 768 + quad * 8);

    floatx4 acc[4] = {};
    #pragma unroll 2
    for (int kk = 0; kk < 24; kk++) {
        int ko = kk * 32;
        floatx4 b0 = *(const floatx4*)(bp + ko);
        floatx4 b1 = *(const floatx4*)(bp + ko + 4);
        bf16x8 bf;
        #pragma unroll
        for (int j = 0; j < 4; j++) { bf[j] = (__bf16)b0[j]; bf[j + 4] = (__bf16)b1[j]; }
        #pragma unroll
        for (int t = 0; t < 4; t++) {
            bf16x8 af = ap[t][kk * 4];
            acc[t] = __builtin_amdgcn_mfma_f32_16x16x32_bf16(af, bf, acc[t], 0, 0, 0);
        }
    }
    float* op = sp + (size_t)ks * ZG_ELEMS + n;
    #pragma unroll
    for (int t = 0; t < 4; t++)
        #pragma unroll
        for (int r = 0; r < 4; r++)
            op[(size_t)((quad << 2) + r + (t << 4)) << 13] = acc[t][r];
}

// einsum GEMM: Znext[b,(o,u)] = sum_{i,a} Zg[b,(i,a)] * (W*clip(mask))[(o,u),(i,a)]
// M=64, N=8192 (o*2048+u), K=8192 (i*2048+a). K-split 8: (i, a-half), 1024 each.
__global__ __launch_bounds__(256) void znext_kernel(const __bf16* __restrict__ zg,
                                                    const float* __restrict__ W,
                                                    const float* __restrict__ mask,
                                                    float* __restrict__ zp) {
    int wave = (blockIdx.x << 2) | (threadIdx.x >> 6);
    int lane = threadIdx.x & 63;
    int col = lane & 15, quad = lane >> 4;
    int ks = wave & 7;
    int ntile = wave >> 3;            // 0..511
    int i = ks >> 1;
    int ah = (ks & 1) << 10;          // a offset 0 / 1024
    int n = (ntile << 4) | col;
    int o = n >> 11, u = n & 2047;

    size_t wbase = ((size_t)((o << 2) + i) * 2048 + u) * 2048 + ah + quad * 8;
    const float* wp = W + wbase;
    const float* mp = mask + wbase;
    const bf16x8* ap[4];
    #pragma unroll
    for (int t = 0; t < 4; t++)
        ap[t] = (const bf16x8*)(zg + (size_t)(((col + 16 * t) << 2) + i) * 2048 + ah + quad * 8);

    floatx4 acc[4] = {};
    #pragma unroll 2
    for (int kk = 0; kk < 32; kk++) {
        int ko = kk * 32;
        floatx4 w0 = *(const floatx4*)(wp + ko);
        floatx4 w1 = *(const floatx4*)(wp + ko + 4);
        floatx4 m0 = *(const floatx4*)(mp + ko);
        floatx4 m1 = *(const floatx4*)(mp + ko + 4);
        bf16x8 bf;
        #pragma unroll
        for (int j = 0; j < 4; j++) {
            bf[j]     = (__bf16)(w0[j] * fminf(fmaxf(m0[j], 0.f), 1.f));
            bf[j + 4] = (__bf16)(w1[j] * fminf(fmaxf(m1[j], 0.f), 1.f));
        }
        #pragma unroll
        for (int t = 0; t < 4; t++) {
            bf16x8 af = ap[t][kk * 4];
            acc[t] = __builtin_amdgcn_mfma_f32_16x16x32_bf16(af, bf, acc[t], 0, 0, 0);
        }
    }
    float* op = zp + (size_t)ks * ZG_ELEMS + n;
    #pragma unroll
    for (int t = 0; t < 4; t++)
        #pragma unroll
        for (int r = 0; r < 4; r++)
            op[(size_t)((quad << 2) + r + (t << 4)) << 13] = acc[t][r];
}

// Sum partials, add bias/stim, tanh, scatter via area_idx.
__global__ void epilogue_kernel(const float* __restrict__ zp, const float* __restrict__ sp,
                                const float* __restrict__ rb, const float* __restrict__ gate,
                                const float* __restrict__ bias, const float* __restrict__ Fs,
                                const float* __restrict__ Z, const int* __restrict__ aidx,
                                float* __restrict__ zflat) {
    int e = blockIdx.x * 256 + threadIdx.x;   // 0..524287 = b*8192 + n
    int n = e & 8191;
    int o = n >> 11;
    float zn = 0.f;
    #pragma unroll
    for (int k = 0; k < 8; k++) zn += zp[(size_t)k * ZG_ELEMS + e];
    float st = rb[n];
    #pragma unroll
    for (int k = 0; k < 4; k++) st += sp[(size_t)k * ZG_ELEMS + e];
    float f = Fs[e] * 0.8f + Z[e] * 0.4f;
    float v = tanhf(zn + gate[o] * bias[n] + st - f);
    int b = e >> 13;
    zflat[((size_t)b << 13) + aidx[n]] = v;
}

// raw = Z_flat @ out_w.T + out_b; out[:, :10]=raw, out[:,10]=sigmoid(raw)
__global__ void out_kernel(const float* __restrict__ zflat, const float* __restrict__ ow,
                           const float* __restrict__ ob, float* __restrict__ out) {
    int bid = blockIdx.x;                 // 0..703
    int b = bid / 11, j = bid - b * 11;
    const float* zr = zflat + (size_t)b * 8192;
    const float* wr = ow + (size_t)j * 8192;
    float s = 0.f;
    for (int n = threadIdx.x; n < 8192; n += 256) s += zr[n] * wr[n];
    #pragma unroll
    for (int off = 32; off > 0; off >>= 1) s += __shfl_down(s, off);
    __shared__ float red[4];
    if ((threadIdx.x & 63) == 0) red[threadIdx.x >> 6] = s;
    __syncthreads();
    if (threadIdx.x == 0) {
        float t = red[0] + red[1] + red[2] + red[3] + ob[j];
        out[bid] = (j == 10) ? 1.f / (1.f + expf(-t)) : t;
    }
}

extern "C" void kernel_launch(void* const* d_in, const int* in_sizes, int n_in,
                              void* d_out, int out_size, void* d_ws, size_t ws_size,
                              hipStream_t stream) {
    const float* x    = (const float*)d_in[0];
    const float* Z    = (const float*)d_in[1];
    const float* Fs   = (const float*)d_in[2];
    const float* rw   = (const float*)d_in[3];
    const float* rb   = (const float*)d_in[4];
    const float* W    = (const float*)d_in[5];
    const float* mask = (const float*)d_in[6];
    const float* bias = (const float*)d_in[7];
    const float* ow   = (const float*)d_in[8];
    const float* ob   = (const float*)d_in[9];
    const int*   aidx = (const int*)d_in[10];
    float* out = (float*)d_out;

    char* ws = (char*)d_ws;
    float*  gate  = (float*)(ws + 0);
    __bf16* zg    = (__bf16*)(ws + 256);
    __bf16* xb    = (__bf16*)(ws + 1048832);
    float*  sp    = (float*)(ws + 1442048);
    float*  zp    = (float*)(ws + 9830656);
    float*  zflat = (float*)(ws + 26607872);

    gate_kernel<<<4, 256, 0, stream>>>(Z, gate);
    prep_kernel<<<2816, 256, 0, stream>>>(Z, x, gate, zg, xb, zflat);
    stim_kernel<<<512, 256, 0, stream>>>(xb, rw, sp);
    znext_kernel<<<1024, 256, 0, stream>>>(zg, W, mask, zp);
    epilogue_kernel<<<2048, 256, 0, stream>>>(zp, sp, rb, gate, bias, Fs, Z, aidx, zflat);
    out_kernel<<<704, 256, 0, stream>>>(zflat, ow, ob, out);
}

// Round 2
// 684.199 us; speedup vs baseline: 1.2673x; 1.2673x over previous
//
#include <hip/hip_runtime.h>
#include <hip/hip_bf16.h>

// BiologicalBrain: B=64, D=3072, NA=4, A=2048, N=8192
// R1: gate_kernel (243us, 4-block latency-bound) deleted. Gate abs-sum fused
// into prep_kernel (which already streams Z); gating applied as a scalar
// multiply on znext accumulators (gate factors out of the k-sum per area) and
// recomputed from gsum in the epilogue.
//
// ws layout (bytes):
//   gsum        @ 0         (16 B, zeroed via hipMemsetAsync)
//   Zg bf16     @ 256       (1 MB)
//   x  bf16     @ 1048832   (384 KB)
//   stim parts  @ 1442048   (4 x 2 MB)
//   znext parts @ 9830656   (8 x 2 MB)
//   Z_flat      @ 26607872  (2 MB)

typedef __bf16 bf16x8 __attribute__((ext_vector_type(8)));
typedef float floatx4 __attribute__((ext_vector_type(4)));

#define ZG_ELEMS   524288   // 64*4*2048 = B*N
#define GATE_THRESH (0.02f * 131072.f)   // compare sum vs mean-threshold

// Zg = bf16(Z); x -> bf16; zero Z_flat; fused per-area abs-sum of Z.
// Blocks 0..2047 each cover 256 contiguous elems of one (b,i) row (rows are
// 2048-elem aligned) -> one area per block -> one atomicAdd per block.
__global__ void prep_kernel(const float* __restrict__ Z, const float* __restrict__ x,
                            __bf16* __restrict__ zg, __bf16* __restrict__ xb,
                            float* __restrict__ zflat, float* __restrict__ gsum) {
    int idx = blockIdx.x * 256 + threadIdx.x;
    float v = 0.f;
    if (idx < ZG_ELEMS) {
        float z = Z[idx];
        zg[idx] = (__bf16)z;
        zflat[idx] = 0.f;
        v = fabsf(z);
    } else {
        int k = idx - ZG_ELEMS;
        xb[k] = (__bf16)x[k];
    }
    #pragma unroll
    for (int off = 32; off > 0; off >>= 1) v += __shfl_down(v, off);
    __shared__ float red[4];
    if ((threadIdx.x & 63) == 0) red[threadIdx.x >> 6] = v;
    __syncthreads();
    if (threadIdx.x == 0 && blockIdx.x < 2048) {
        int i = (blockIdx.x >> 3) & 3;   // idx>>11 & 3 with idx = blockIdx*256
        atomicAdd(&gsum[i], red[0] + red[1] + red[2] + red[3]);
    }
}

// stim GEMM: C[b,n] = sum_d x[b,d] * rw[n,d].  M=64, N=8192, K=3072.
// One wave: n-tile of 16 (cols), all 64 b (4 m-tiles), K-split 4 (768 each, 24 steps).
__global__ __launch_bounds__(256) void stim_kernel(const __bf16* __restrict__ xb,
                                                   const float* __restrict__ rw,
                                                   float* __restrict__ sp) {
    int wave = (blockIdx.x << 2) | (threadIdx.x >> 6);
    int lane = threadIdx.x & 63;
    int col = lane & 15, quad = lane >> 4;
    int ks = wave & 3;
    int ntile = wave >> 2;            // 0..511
    int n = (ntile << 4) | col;
    const float* bp = rw + (size_t)n * 3072 + ks * 768 + quad * 8;
    const bf16x8* ap[4];
    #pragma unroll
    for (int t = 0; t < 4; t++)
        ap[t] = (const bf16x8*)(xb + (size_t)(col + 16 * t) * 3072 + ks * 768 + quad * 8);

    floatx4 acc[4] = {};
    #pragma unroll 2
    for (int kk = 0; kk < 24; kk++) {
        int ko = kk * 32;
        floatx4 b0 = *(const floatx4*)(bp + ko);
        floatx4 b1 = *(const floatx4*)(bp + ko + 4);
        bf16x8 bf;
        #pragma unroll
        for (int j = 0; j < 4; j++) { bf[j] = (__bf16)b0[j]; bf[j + 4] = (__bf16)b1[j]; }
        #pragma unroll
        for (int t = 0; t < 4; t++) {
            bf16x8 af = ap[t][kk * 4];
            acc[t] = __builtin_amdgcn_mfma_f32_16x16x32_bf16(af, bf, acc[t], 0, 0, 0);
        }
    }
    float* op = sp + (size_t)ks * ZG_ELEMS + n;
    #pragma unroll
    for (int t = 0; t < 4; t++)
        #pragma unroll
        for (int r = 0; r < 4; r++)
            op[(size_t)((quad << 2) + r + (t << 4)) << 13] = acc[t][r];
}

// einsum GEMM: Znext[b,(o,u)] = sum_{i,a} Zg[b,(i,a)] * (W*clip(mask))[(o,u),(i,a)]
// M=64, N=8192 (o*2048+u), K=8192 (i*2048+a). K-split 8: (i, a-half), 1024 each.
// Gate applied as scalar multiply on the accumulator (factors out per area i).
__global__ __launch_bounds__(256) void znext_kernel(const __bf16* __restrict__ zg,
                                                    const float* __restrict__ W,
                                                    const float* __restrict__ mask,
                                                    const float* __restrict__ gsum,
                                                    float* __restrict__ zp) {
    int wave = (blockIdx.x << 2) | (threadIdx.x >> 6);
    int lane = threadIdx.x & 63;
    int col = lane & 15, quad = lane >> 4;
    int ks = wave & 7;
    int ntile = wave >> 3;            // 0..511
    int i = ks >> 1;
    int ah = (ks & 1) << 10;          // a offset 0 / 1024
    int n = (ntile << 4) | col;
    int o = n >> 11, u = n & 2047;

    size_t wbase = ((size_t)((o << 2) + i) * 2048 + u) * 2048 + ah + quad * 8;
    const float* wp = W + wbase;
    const float* mp = mask + wbase;
    const bf16x8* ap[4];
    #pragma unroll
    for (int t = 0; t < 4; t++)
        ap[t] = (const bf16x8*)(zg + (size_t)(((col + 16 * t) << 2) + i) * 2048 + ah + quad * 8);

    floatx4 acc[4] = {};
    #pragma unroll 2
    for (int kk = 0; kk < 32; kk++) {
        int ko = kk * 32;
        floatx4 w0 = *(const floatx4*)(wp + ko);
        floatx4 w1 = *(const floatx4*)(wp + ko + 4);
        floatx4 m0 = *(const floatx4*)(mp + ko);
        floatx4 m1 = *(const floatx4*)(mp + ko + 4);
        bf16x8 bf;
        #pragma unroll
        for (int j = 0; j < 4; j++) {
            bf[j]     = (__bf16)(w0[j] * fminf(fmaxf(m0[j], 0.f), 1.f));
            bf[j + 4] = (__bf16)(w1[j] * fminf(fmaxf(m1[j], 0.f), 1.f));
        }
        #pragma unroll
        for (int t = 0; t < 4; t++) {
            bf16x8 af = ap[t][kk * 4];
            acc[t] = __builtin_amdgcn_mfma_f32_16x16x32_bf16(af, bf, acc[t], 0, 0, 0);
        }
    }
    float gv = (gsum[i] > GATE_THRESH) ? 1.f : 0.f;
    float* op = zp + (size_t)ks * ZG_ELEMS + n;
    #pragma unroll
    for (int t = 0; t < 4; t++)
        #pragma unroll
        for (int r = 0; r < 4; r++)
            op[(size_t)((quad << 2) + r + (t << 4)) << 13] = acc[t][r] * gv;
}

// Sum partials, add bias/stim, tanh, scatter via area_idx.
__global__ void epilogue_kernel(const float* __restrict__ zp, const float* __restrict__ sp,
                                const float* __restrict__ rb, const float* __restrict__ gsum,
                                const float* __restrict__ bias, const float* __restrict__ Fs,
                                const float* __restrict__ Z, const int* __restrict__ aidx,
                                float* __restrict__ zflat) {
    int e = blockIdx.x * 256 + threadIdx.x;   // 0..524287 = b*8192 + n
    int n = e & 8191;
    int o = n >> 11;
    float zn = 0.f;
    #pragma unroll
    for (int k = 0; k < 8; k++) zn += zp[(size_t)k * ZG_ELEMS + e];
    float st = rb[n];
    #pragma unroll
    for (int k = 0; k < 4; k++) st += sp[(size_t)k * ZG_ELEMS + e];
    float gv = (gsum[o] > GATE_THRESH) ? 1.f : 0.f;
    float f = Fs[e] * 0.8f + Z[e] * 0.4f;
    float v = tanhf(zn + gv * bias[n] + st - f);
    int b = e >> 13;
    zflat[((size_t)b << 13) + aidx[n]] = v;
}

// raw = Z_flat @ out_w.T + out_b; out[:, :10]=raw, out[:,10]=sigmoid(raw)
__global__ void out_kernel(const float* __restrict__ zflat, const float* __restrict__ ow,
                           const float* __restrict__ ob, float* __restrict__ out) {
    int bid = blockIdx.x;                 // 0..703
    int b = bid / 11, j = bid - b * 11;
    const float* zr = zflat + (size_t)b * 8192;
    const float* wr = ow + (size_t)j * 8192;
    float s = 0.f;
    for (int n = threadIdx.x; n < 8192; n += 256) s += zr[n] * wr[n];
    #pragma unroll
    for (int off = 32; off > 0; off >>= 1) s += __shfl_down(s, off);
    __shared__ float red[4];
    if ((threadIdx.x & 63) == 0) red[threadIdx.x >> 6] = s;
    __syncthreads();
    if (threadIdx.x == 0) {
        float t = red[0] + red[1] + red[2] + red[3] + ob[j];
        out[bid] = (j == 10) ? 1.f / (1.f + expf(-t)) : t;
    }
}

extern "C" void kernel_launch(void* const* d_in, const int* in_sizes, int n_in,
                              void* d_out, int out_size, void* d_ws, size_t ws_size,
                              hipStream_t stream) {
    const float* x    = (const float*)d_in[0];
    const float* Z    = (const float*)d_in[1];
    const float* Fs   = (const float*)d_in[2];
    const float* rw   = (const float*)d_in[3];
    const float* rb   = (const float*)d_in[4];
    const float* W    = (const float*)d_in[5];
    const float* mask = (const float*)d_in[6];
    const float* bias = (const float*)d_in[7];
    const float* ow   = (const float*)d_in[8];
    const float* ob   = (const float*)d_in[9];
    const int*   aidx = (const int*)d_in[10];
    float* out = (float*)d_out;

    char* ws = (char*)d_ws;
    float*  gsum  = (float*)(ws + 0);
    __bf16* zg    = (__bf16*)(ws + 256);
    __bf16* xb    = (__bf16*)(ws + 1048832);
    float*  sp    = (float*)(ws + 1442048);
    float*  zp    = (float*)(ws + 9830656);
    float*  zflat = (float*)(ws + 26607872);

    hipMemsetAsync(gsum, 0, 16, stream);
    prep_kernel<<<2816, 256, 0, stream>>>(Z, x, zg, xb, zflat, gsum);
    stim_kernel<<<512, 256, 0, stream>>>(xb, rw, sp);
    znext_kernel<<<1024, 256, 0, stream>>>(zg, W, mask, gsum, zp);
    epilogue_kernel<<<2048, 256, 0, stream>>>(zp, sp, rb, gsum, bias, Fs, Z, aidx, zflat);
    out_kernel<<<704, 256, 0, stream>>>(zflat, ow, ob, out);
}